// Round 1
// baseline (865.476 us; speedup 1.0000x reference)
//
#include <hip/hip_runtime.h>

using half8 = __attribute__((ext_vector_type(8))) _Float16;
using half4 = __attribute__((ext_vector_type(4))) _Float16;
using f32x4 = __attribute__((ext_vector_type(4))) float;

// ws layout (bytes)
#define OFF_XPROJ 0ULL                 // 8192*2048*2  = 33554432
#define OFF_WHH   33554432ULL          // 2048*512*2   = 2097152
#define OFF_WC    35651584ULL          // 2048*256*2   = 1048576
#define OFF_WCF32 36700160ULL          // 2048*256*4   = 2097152
#define OFF_BC    38797312ULL          // 2048*4
#define OFF_B0    38805504ULL          // 2048*4

__device__ __forceinline__ float sigm(float x){ return 1.0f/(1.0f + __expf(-x)); }
__device__ __forceinline__ float tanh_(float x){ float e = __expf(2.0f*x); return 1.0f - 2.0f/(e + 1.0f); }

// ---------------- prep1: Wc = w_ih @ conv_w (fp32), combined biases (permuted) ----
__global__ void prep1(const float* __restrict__ conv_w, const float* __restrict__ conv_b,
                      const float* __restrict__ w_ih, const float* __restrict__ b_ih,
                      const float* __restrict__ b_hh, float* __restrict__ Wc,
                      float* __restrict__ bc_perm, float* __restrict__ b0_perm){
  int bid = blockIdx.x, t = threadIdx.x;
  if (bid < 256) {
    int r0 = bid*8;
    float acc[8];
    #pragma unroll
    for (int i=0;i<8;++i) acc[i]=0.f;
    for (int d=0; d<512; ++d){
      float cw = conv_w[d*256 + t];
      #pragma unroll
      for (int i=0;i<8;++i) acc[i] = fmaf(w_ih[(r0+i)*512+d], cw, acc[i]);
    }
    #pragma unroll
    for (int i=0;i<8;++i) Wc[(r0+i)*256 + t] = acc[i];
  } else {
    int r = (bid-256)*256 + t;          // 0..2047
    float s = 0.f;
    for (int d=0; d<512; ++d) s = fmaf(w_ih[r*512+d], conv_b[d], s);
    int gate = r >> 9, u = r & 511;
    int newc = ((u>>4)<<6) + (gate<<4) + (u&15);
    float bb = b_ih[r] + b_hh[r];
    b0_perm[newc] = bb;          // padded-step bias (no conv_b term!)
    bc_perm[newc] = s + bb;      // in-bounds bias (conv_b folded through w_ih)
  }
}

// ---------------- prep2: swizzle w_hh and Wc into MFMA B-fragment order (fp16) ----
// frag element (s,t,lane,j) = W[row r(newc = t*16 + (lane&15))][k = s*32 + (lane>>4)*8 + j]
__global__ void prep2(const float* __restrict__ w_hh, const float* __restrict__ Wc,
                      _Float16* __restrict__ whh_f, _Float16* __restrict__ wc_f){
  int e = blockIdx.x*256 + threadIdx.x;     // 6144*256 = 2^20 + 2^19 exactly
  if (e < (1<<20)) {
    int j = e&7, lane = (e>>3)&63, t = (e>>9)&127, s = e>>16;   // s: 0..15
    int newc = t*16 + (lane&15);
    int k = s*32 + (lane>>4)*8 + j;
    int r = (((newc>>4)&3)<<9) + ((newc>>6)<<4) + (newc&15);
    whh_f[e] = (_Float16)w_hh[r*512 + k];
  } else {
    int e2 = e - (1<<20);
    int j = e2&7, lane = (e2>>3)&63, t = (e2>>9)&127, s = e2>>16; // s: 0..7
    int newc = t*16 + (lane&15);
    int k = s*32 + (lane>>4)*8 + j;
    int r = (((newc>>4)&3)<<9) + ((newc>>6)<<4) + (newc&15);
    wc_f[e2] = (_Float16)Wc[r*256 + k];
  }
}

// ---------------- xp: xproj = glu(x) @ Wc.T + bc  (fp16 out, permuted cols) -------
__global__ __launch_bounds__(512, 2) void xp_kernel(const float* __restrict__ x,
      const _Float16* __restrict__ wc_f, const float* __restrict__ bc_perm,
      _Float16* __restrict__ xproj){
  __shared__ _Float16 A[32*264];            // 32 rows x 256, pitch 264 (16B aligned rows)
  int wg = blockIdx.x, tid = threadIdx.x;
  int n0 = wg*32;
  int wv = tid>>6, lane = tid&63, lrow = lane>>4, lcol = lane&15;
  // stage GLU tile, coalesced
  #pragma unroll
  for (int i=0;i<4;++i){
    int q = tid + i*512;                    // 0..2047
    int row = q>>6, pos = q&63;
    const float* xr = x + (size_t)(n0+row)*512;
    float4 va = *(const float4*)(xr + pos*4);
    float4 vb = *(const float4*)(xr + 256 + pos*4);
    half4 h;
    h[0] = (_Float16)(va.x / (1.f+__expf(-vb.x)));
    h[1] = (_Float16)(va.y / (1.f+__expf(-vb.y)));
    h[2] = (_Float16)(va.z / (1.f+__expf(-vb.z)));
    h[3] = (_Float16)(va.w / (1.f+__expf(-vb.w)));
    *(half4*)&A[row*264 + pos*4] = h;
  }
  f32x4 acc[2][16];
  #pragma unroll
  for (int nt=0;nt<16;++nt){
    int col = (wv*16+nt)*16 + lcol;
    float b = bc_perm[col];
    f32x4 v = {b,b,b,b};
    acc[0][nt]=v; acc[1][nt]=v;
  }
  __syncthreads();
  for (int s=0;s<8;++s){
    half8 a0 = *(const half8*)&A[lcol*264 + s*32 + lrow*8];
    half8 a1 = *(const half8*)&A[(16+lcol)*264 + s*32 + lrow*8];
    #pragma unroll
    for (int nt=0;nt<16;++nt){
      int t = wv*16+nt;
      half8 b = *(const half8*)(wc_f + ((s*128 + t)*64 + lane)*8);
      acc[0][nt] = __builtin_amdgcn_mfma_f32_16x16x32_f16(a0, b, acc[0][nt], 0,0,0);
      acc[1][nt] = __builtin_amdgcn_mfma_f32_16x16x32_f16(a1, b, acc[1][nt], 0,0,0);
    }
  }
  #pragma unroll
  for (int m=0;m<2;++m)
    #pragma unroll
    for (int nt=0;nt<16;++nt){
      int col = (wv*16+nt)*16 + lcol;
      #pragma unroll
      for (int reg=0;reg<4;++reg){
        int n = n0 + m*16 + lrow*4 + reg;
        xproj[n*2048 + col] = (_Float16)acc[m][nt][reg];
      }
    }
}

// ---------------- lstm: persistent, 32 rows/WG, 9 steps, no inter-WG deps --------
__global__ __launch_bounds__(512, 2) void lstm_kernel(const _Float16* __restrict__ xproj,
      const _Float16* __restrict__ whh_f, const float* __restrict__ b0_perm,
      float* __restrict__ out){
  __shared__ _Float16 H[32*520];            // pitch 520 (16B-aligned, bank-spread)
  int wg = blockIdx.x, tid = threadIdx.x;
  int n0 = wg*32, l0 = n0 & 511;
  int wv = tid>>6, lane = tid&63, lrow = lane>>4, lcol = lane&15;
  f32x4 c[2][4];
  #pragma unroll
  for (int m=0;m<2;++m)
    #pragma unroll
    for (int ub=0;ub<4;++ub) c[m][ub] = (f32x4){0.f,0.f,0.f,0.f};
  float b0v[16];
  #pragma unroll
  for (int nt=0;nt<16;++nt) b0v[nt] = b0_perm[(wv*16+nt)*16 + lcol];

  #pragma unroll 1
  for (int k=0;k<9;++k){
    f32x4 acc[2][16];
    // gather input-projection gates (window shift = k-8; OOB -> bias-only)
    #pragma unroll
    for (int m=0;m<2;++m)
      #pragma unroll
      for (int nt=0;nt<16;++nt){
        int col = (wv*16+nt)*16 + lcol;
        #pragma unroll
        for (int reg=0;reg<4;++reg){
          int rl = m*16 + lrow*4 + reg;
          int lx = l0 + rl + k - 8;
          int xrow = (lx < 0) ? n0 : (n0 + rl + k - 8);
          float xv = (float)xproj[xrow*2048 + col];
          acc[m][nt][reg] = (lx < 0) ? b0v[nt] : xv;
        }
      }
    // recurrent GEMM: gates += h @ w_hh.T  (skip at k==0, h=0)
    if (k > 0){
      for (int s=0;s<16;++s){
        half8 a0 = *(const half8*)&H[lcol*520 + s*32 + lrow*8];
        half8 a1 = *(const half8*)&H[(16+lcol)*520 + s*32 + lrow*8];
        #pragma unroll
        for (int nt=0;nt<16;++nt){
          int t = wv*16+nt;
          half8 b = *(const half8*)(whh_f + ((s*128 + t)*64 + lane)*8);
          acc[0][nt] = __builtin_amdgcn_mfma_f32_16x16x32_f16(a0, b, acc[0][nt],0,0,0);
          acc[1][nt] = __builtin_amdgcn_mfma_f32_16x16x32_f16(a1, b, acc[1][nt],0,0,0);
        }
      }
    }
    __syncthreads();   // all waves done reading H before it is overwritten
    // elementwise LSTM update: i,f,g,o are 4 adjacent N-tiles, same lane/reg
    #pragma unroll
    for (int m=0;m<2;++m)
      #pragma unroll
      for (int ub=0;ub<4;++ub){
        f32x4 gi = acc[m][ub*4+0], gf = acc[m][ub*4+1];
        f32x4 gg = acc[m][ub*4+2], go = acc[m][ub*4+3];
        #pragma unroll
        for (int reg=0;reg<4;++reg){
          float ci = sigm(gf[reg])*c[m][ub][reg] + sigm(gi[reg])*tanh_(gg[reg]);
          c[m][ub][reg] = ci;
          float h = sigm(go[reg])*tanh_(ci);
          int row = m*16 + lrow*4 + reg;
          int u = (wv*4+ub)*16 + lcol;
          if (k < 8) H[row*520 + u] = (_Float16)h;
          else       out[(size_t)(n0+row)*512 + u] = h;   // fp32 h, full precision
        }
      }
    __syncthreads();
  }
}

extern "C" void kernel_launch(void* const* d_in, const int* in_sizes, int n_in,
                              void* d_out, int out_size, void* d_ws, size_t ws_size,
                              hipStream_t stream){
  const float* x      = (const float*)d_in[0];
  const float* conv_w = (const float*)d_in[1];
  const float* conv_b = (const float*)d_in[2];
  const float* w_ih   = (const float*)d_in[3];
  const float* w_hh   = (const float*)d_in[4];
  const float* b_ih   = (const float*)d_in[5];
  const float* b_hh   = (const float*)d_in[6];
  char* ws = (char*)d_ws;
  _Float16* xproj = (_Float16*)(ws + OFF_XPROJ);
  _Float16* whh_f = (_Float16*)(ws + OFF_WHH);
  _Float16* wc_f  = (_Float16*)(ws + OFF_WC);
  float* Wc       = (float*)(ws + OFF_WCF32);
  float* bc_perm  = (float*)(ws + OFF_BC);
  float* b0_perm  = (float*)(ws + OFF_B0);
  float* out = (float*)d_out;

  prep1<<<264, 256, 0, stream>>>(conv_w, conv_b, w_ih, b_ih, b_hh, Wc, bc_perm, b0_perm);
  prep2<<<6144, 256, 0, stream>>>(w_hh, Wc, whh_f, wc_f);
  xp_kernel<<<256, 512, 0, stream>>>(x, wc_f, bc_perm, xproj);
  lstm_kernel<<<256, 512, 0, stream>>>(xproj, whh_f, b0_perm, out);
}